// Round 20
// baseline (246.420 us; speedup 1.0000x reference)
//
#include <hip/hip_runtime.h>
#include <hip/hip_bf16.h>

// Problem constants (from reference)
#define NB   64          // graphs
#define NPG  2048        // nodes per graph
#define NN   (NB*NPG)    // 131072 total nodes
#define EPG  32768       // edges per graph
#define EE   (NB*EPG)    // 2097152 edges
#define DD   32          // feature dim
#define KK   1024        // kept nodes per graph (ratio 0.5)

typedef unsigned long long u64;
typedef unsigned int u32;

// Packed dual-FP32 FMA (VOP3P), all operands 64-bit pairs (R19 failed with
// a single-VGPR src0 — assembler requires pairs). acc and s2 are node-packed
// (lo=node0, hi=node1); w's LO or HI half is broadcast to both lanes via
// op_sel. Per-lane IEEE fma -> each node's chain rounding == scalar chain.
__device__ __forceinline__ void pk_fma_wlo(float2& acc, float2 s2, float2 w) {
    // both lanes use w.lo: src1 lo=lo (op_sel[1]=0), src1 hi=lo (op_sel_hi[1]=0)
    asm("v_pk_fma_f32 %0, %1, %2, %0 op_sel:[0,0,0] op_sel_hi:[1,0,1]"
        : "+v"(acc) : "v"(s2), "v"(w));
}
__device__ __forceinline__ void pk_fma_whi(float2& acc, float2 s2, float2 w) {
    // both lanes use w.hi: src1 lo=hi (op_sel[1]=1), src1 hi=hi (op_sel_hi[1]=1)
    asm("v_pk_fma_f32 %0, %1, %2, %0 op_sel:[0,1,0] op_sel_hi:[1,1,1]"
        : "+v"(acc) : "v"(s2), "v"(w));
}

// ---------------------------------------------------------------------------
// K1a: per-sub-block histogram. 256 blocks: graph g = b&63, sub s = b>>6,
// 8192 edges each. LDS histogram -> global hist[s][g][n]. Integer atomics
// commute -> counts deterministic.
// ---------------------------------------------------------------------------
__global__ __launch_bounds__(1024) void hist_kernel(
    const int* __restrict__ dst, int* __restrict__ hist)
{
    __shared__ int cnt[NPG];
    int b = blockIdx.x;
    int t = threadIdx.x;
    int g = b & 63, s = b >> 6;
    for (int i = t; i < NPG; i += 1024) cnt[i] = 0;
    __syncthreads();
    const int ebase = g * EPG + s * 8192;
    const int nbase = g * NPG;
#pragma unroll
    for (int q = 0; q < 8; q++) {
        int e = ebase + q * 1024 + t;
        atomicAdd(&cnt[dst[e] - nbase], 1);
    }
    __syncthreads();
    int* hb = hist + (s * 64 + g) * NPG;
    for (int i = t; i < NPG; i += 1024) hb[i] = cnt[i];
}

// ---------------------------------------------------------------------------
// K1b: per-graph scan. 64 blocks. Sums the 4 sub-histograms -> counts,
// exclusive-scans totals -> offsets, and emits per-sub-block start cursors.
// ---------------------------------------------------------------------------
__global__ __launch_bounds__(1024) void scan2_kernel(
    const int* __restrict__ hist,
    int* __restrict__ counts, int* __restrict__ offsets,
    int* __restrict__ cursors)
{
    __shared__ int tot[1024];
    int g = blockIdx.x;
    int t = threadIdx.x;
    int n0 = 2 * t, n1 = 2 * t + 1;
    int h0[4], h1[4];
#pragma unroll
    for (int s = 0; s < 4; s++) {
        h0[s] = hist[(s * 64 + g) * NPG + n0];
        h1[s] = hist[(s * 64 + g) * NPG + n1];
    }
    int c0 = h0[0] + h0[1] + h0[2] + h0[3];
    int c1 = h1[0] + h1[1] + h1[2] + h1[3];
    tot[t] = c0 + c1;
    __syncthreads();
    for (int o = 1; o < 1024; o <<= 1) {
        int v = tot[t];
        int u = (t >= o) ? tot[t - o] : 0;
        __syncthreads();
        tot[t] = v + u;
        __syncthreads();
    }
    int excl = (t == 0) ? 0 : tot[t - 1];
    int nbase = g * NPG;
    counts[nbase + n0] = c0;
    counts[nbase + n1] = c1;
    int off0 = g * EPG + excl;
    int off1 = off0 + c0;
    offsets[nbase + n0] = off0;
    offsets[nbase + n1] = off1;
    int a0 = off0, a1 = off1;
#pragma unroll
    for (int s = 0; s < 4; s++) {
        cursors[(s * 64 + g) * NPG + n0] = a0; a0 += h0[s];
        cursors[(s * 64 + g) * NPG + n1] = a1; a1 += h1[s];
    }
}

// ---------------------------------------------------------------------------
// K1c: scatter. 256 blocks, same (g,s) mapping -> all 4 writer blocks of a
// graph satisfy b%8 == g%8 (same-XCD heuristic) -> no cross-XCD write amp.
// Bucket ORDER from atomics is nondeterministic (multiset is deterministic);
// downstream aggregation is order-INVARIANT (fixed-point) so this is safe.
// ---------------------------------------------------------------------------
__global__ __launch_bounds__(1024) void scatter_kernel(
    const int* __restrict__ src, const int* __restrict__ dst,
    const int* __restrict__ cursors, int* __restrict__ edge_ids)
{
    __shared__ int cur[NPG];
    int b = blockIdx.x;
    int t = threadIdx.x;
    int g = b & 63, s = b >> 6;
    const int* cb = cursors + (s * 64 + g) * NPG;
    for (int i = t; i < NPG; i += 1024) cur[i] = cb[i];
    __syncthreads();
    const int ebase = g * EPG + s * 8192;
    const int nbase = g * NPG;
#pragma unroll
    for (int q = 0; q < 8; q++) {
        int e = ebase + q * 1024 + t;
        int pos = atomicAdd(&cur[dst[e] - nbase], 1);
        edge_ids[pos] = src[e];
    }
}

// ---------------------------------------------------------------------------
// K2a: aggregation — agg[n] = sum_{s in N(n)} x[s]. 8 threads per node.
// FIXED-POINT int32 accumulation (scale 2^22): integer adds commute exactly
// -> agg identical for ANY bucket order -> replay-deterministic (R18 fix).
// Overflow: |sum| <= ~40*8*2^22 ~ 1.3e9 < 2^31. XCD-affinity swizzle.
// ---------------------------------------------------------------------------
__global__ __launch_bounds__(256) void agg_kernel(
    const float* __restrict__ x,
    const int* __restrict__ counts, const int* __restrict__ offsets,
    const int* __restrict__ edge_ids,
    float* __restrict__ agg)
{
    const float SCALE  = 4194304.0f;             // 2^22
    const float ISCALE = 2.38418579101562e-07f;  // 2^-22
    int b = blockIdx.x;                          // 0..4095
    int c = (b & 7) * 512 + (b >> 3);            // bijection on [0,4096)
    int tid = c * 256 + threadIdx.x;             // NN*8 threads
    int node = tid >> 3;
    int ch = (tid & 7) * 4;
    int deg  = counts[node];
    int base = offsets[node];
    int ax = 0, ay = 0, az = 0, aw = 0;
    for (int k = 0; k < deg; k++) {
        int s = edge_ids[base + k];
        float4 v = *(const float4*)(x + (long long)s * DD + ch);
        ax += __float2int_rn(v.x * SCALE);
        ay += __float2int_rn(v.y * SCALE);
        az += __float2int_rn(v.z * SCALE);
        aw += __float2int_rn(v.w * SCALE);
    }
    float4 r;
    r.x = (float)ax * ISCALE;
    r.y = (float)ay * ISCALE;
    r.z = (float)az * ISCALE;
    r.w = (float)aw * ISCALE;
    *(float4*)(agg + (long long)node * DD + ch) = r;
}

// ---------------------------------------------------------------------------
// K2b: per-node score = <x2, y2> / sqrt(32). fp32 W in LDS (ds_read_b128).
// R=2 node-pairing (i, i+NN/2) + 2-way d-split (R12 structure). R20: the
// two nodes are PACKED into lo/hi lanes of float2 accumulators and the
// inner product runs on forced v_pk_fma_f32 (op_sel broadcasts the W half)
// — score was VALU-bound at scalar fma rate (27us of ~36); packed halves
// the VALU slots (32 fma -> 16 pk + 4 mov per k). Each node's chain is the
// lane-exact R18 sequence -> bit-exact. ESTABLISHED (R13): score must stay
// fp32-accurate; only rounding-class-preserving changes are safe.
// ---------------------------------------------------------------------------
__global__ __launch_bounds__(256) void score_kernel(
    const float* __restrict__ x, const float* __restrict__ agg,
    const float* __restrict__ Wr1, const float* __restrict__ Wl1, const float* __restrict__ b1,
    const float* __restrict__ Wr2, const float* __restrict__ Wl2, const float* __restrict__ b2,
    float* __restrict__ score)
{
    __shared__ float4 sWr1[DD*DD/4], sWl1[DD*DD/4], sWr2[DD*DD/4], sWl2[DD*DD/4];
    __shared__ float sb1[DD], sb2[DD];
    __shared__ float2 part[128];
    {
        int t = threadIdx.x;             // 256 threads, 256 float4 per matrix
        sWr1[t] = ((const float4*)Wr1)[t];
        sWl1[t] = ((const float4*)Wl1)[t];
        sWr2[t] = ((const float4*)Wr2)[t];
        sWl2[t] = ((const float4*)Wl2)[t];
        if (t < DD) { sb1[t] = b1[t]; sb2[t] = b2[t]; }
    }
    __syncthreads();

    int lane = threadIdx.x & 127;
    int half = threadIdx.x >> 7;                 // 0: d0 0-3, 1: d0 4-7
    int i0 = blockIdx.x * 128 + lane;            // 0 .. NN/2-1
    int i1 = i0 + NN/2;                          // second dense stream

    float xv0[DD], av0[DD], xv1[DD], av1[DD];
    {
        const float4* xp0 = (const float4*)(x + (long long)i0 * DD);
        const float4* ap0 = (const float4*)(agg + (long long)i0 * DD);
        const float4* xp1 = (const float4*)(x + (long long)i1 * DD);
        const float4* ap1 = (const float4*)(agg + (long long)i1 * DD);
#pragma unroll
        for (int q = 0; q < 8; q++) {
            float4 v0 = xp0[q]; xv0[4*q]=v0.x; xv0[4*q+1]=v0.y; xv0[4*q+2]=v0.z; xv0[4*q+3]=v0.w;
            float4 w0 = ap0[q]; av0[4*q]=w0.x; av0[4*q+1]=w0.y; av0[4*q+2]=w0.z; av0[4*q+3]=w0.w;
            float4 v1 = xp1[q]; xv1[4*q]=v1.x; xv1[4*q+1]=v1.y; xv1[4*q+2]=v1.z; xv1[4*q+3]=v1.w;
            float4 w1 = ap1[q]; av1[4*q]=w1.x; av1[4*q+1]=w1.y; av1[4*q+2]=w1.z; av1[4*q+3]=w1.w;
        }
    }

    float sc0 = 0.f, sc1 = 0.f;
    int dbase = half * 4;
    for (int dd = 0; dd < 4; dd++) {             // this thread's 4 d0-blocks
        int d0 = dbase + dd;
        // node-packed accumulators: a01[j] = (a_node0[j], a_node1[j])
        float2 a01[4], q01[4];
#pragma unroll
        for (int j = 0; j < 4; j++) {
            float bb1 = sb1[4*d0+j], bb2 = sb2[4*d0+j];
            a01[j] = make_float2(bb1, bb1);
            q01[j] = make_float2(bb2, bb2);
        }
#pragma unroll
        for (int k = 0; k < DD; k++) {
            float4 wr1 = sWr1[k*8 + d0];
            float4 wl1 = sWl1[k*8 + d0];
            float4 wr2 = sWr2[k*8 + d0];
            float4 wl2 = sWl2[k*8 + d0];
            float2 r1l = make_float2(wr1.x, wr1.y), r1h = make_float2(wr1.z, wr1.w);
            float2 l1l = make_float2(wl1.x, wl1.y), l1h = make_float2(wl1.z, wl1.w);
            float2 r2l = make_float2(wr2.x, wr2.y), r2h = make_float2(wr2.z, wr2.w);
            float2 l2l = make_float2(wl2.x, wl2.y), l2h = make_float2(wl2.z, wl2.w);
            float2 xk01 = make_float2(xv0[k], xv1[k]);
            float2 ak01 = make_float2(av0[k], av1[k]);
            // per-chain order == R18: a += xk*Wr1[j]; a += ak*Wl1[j];
            //                         q += xk*Wr2[j]; q += ak*Wl2[j]
            pk_fma_wlo(a01[0], xk01, r1l);  pk_fma_whi(a01[1], xk01, r1l);
            pk_fma_wlo(a01[2], xk01, r1h);  pk_fma_whi(a01[3], xk01, r1h);
            pk_fma_wlo(a01[0], ak01, l1l);  pk_fma_whi(a01[1], ak01, l1l);
            pk_fma_wlo(a01[2], ak01, l1h);  pk_fma_whi(a01[3], ak01, l1h);
            pk_fma_wlo(q01[0], xk01, r2l);  pk_fma_whi(q01[1], xk01, r2l);
            pk_fma_wlo(q01[2], xk01, r2h);  pk_fma_whi(q01[3], xk01, r2h);
            pk_fma_wlo(q01[0], ak01, l2l);  pk_fma_whi(q01[1], ak01, l2l);
            pk_fma_wlo(q01[2], ak01, l2h);  pk_fma_whi(q01[3], ak01, l2h);
        }
        // dot in fixed j order (j0..j3) == R18
#pragma unroll
        for (int j = 0; j < 4; j++) {
            sc0 += a01[j].x * q01[j].x;
            sc1 += a01[j].y * q01[j].y;
        }
    }

    if (half) { part[lane].x = sc0; part[lane].y = sc1; }
    __syncthreads();
    if (!half) {
        float2 p = part[lane];
        score[i0] = (sc0 + p.x) * 0.17677669529663687f;   // 1/sqrt(32)
        score[i1] = (sc1 + p.y) * 0.17677669529663687f;
    }
}

// ---------------------------------------------------------------------------
// K3: per-graph top-K via bitonic sort of 2048 packed keys in LDS. Unique
// keys (idx in low bits) -> total order -> deterministic. Also initializes
// new_idx for ALL nodes (kept -> new label, dropped -> -1).
// ---------------------------------------------------------------------------
__global__ __launch_bounds__(1024) void topk_kernel(
    const float* __restrict__ score,
    int* __restrict__ perm_int, int* __restrict__ new_idx,
    float* __restrict__ out_perm,
    float* __restrict__ out_batch,
    float* __restrict__ out_score)
{
    __shared__ u64 keys[NPG];
    int b = blockIdx.x;
    int t = threadIdx.x;
    const float* s = score + (long long)b * NPG;

    for (int j = t; j < NPG; j += 1024) {
        u32 u = __float_as_uint(s[j]);
        u32 h = (u & 0x80000000u) ? u : ~(u | 0x80000000u);
        keys[j] = ((u64)h << 32) | (u32)j;
    }

    for (int k = 2; k <= NPG; k <<= 1) {
        for (int j = k >> 1; j > 0; j >>= 1) {
            __syncthreads();
            int i = ((t & ~(j - 1)) << 1) | (t & (j - 1));
            int l = i | j;
            u64 a = keys[i], c = keys[l];
            bool up = ((i & k) == 0);
            if ((a > c) == up) { keys[i] = c; keys[l] = a; }
        }
    }
    __syncthreads();

    // kept half: ranks 0..KK-1 (thread t owns rank t)
    u64 kk = keys[t];
    int idx = (int)(u32)(kk & 0xFFFFFFFFu);
    int g = b * NPG + idx;
    int o = b * KK + t;
    perm_int[o] = g;
    new_idx[g] = o;
    out_perm[o]  = (float)g;
    out_batch[o] = (float)b;
    out_score[o] = s[idx];

    // dropped half: ranks KK..NPG-1 -> new_idx = -1 (replaces memset)
    u64 kd = keys[t + KK];
    int idxd = (int)(u32)(kd & 0xFFFFFFFFu);
    new_idx[b * NPG + idxd] = -1;
}

// ---------------------------------------------------------------------------
// K4: x5 = x[g] + score[g] * (x[g]@Wr3 + agg[g]@Wl3 + b3), kept nodes only.
// d-split: two threads per node; fp32 W in LDS. (Unchanged from R18.)
// ---------------------------------------------------------------------------
__global__ __launch_bounds__(256) void x5_kernel(
    const float* __restrict__ x, const float* __restrict__ agg,
    const float* __restrict__ Wr3, const float* __restrict__ Wl3, const float* __restrict__ b3,
    const int* __restrict__ perm_int, const float* __restrict__ score,
    float* __restrict__ out_x5)
{
    __shared__ float4 sWr[DD*DD/4], sWl[DD*DD/4];
    __shared__ float sb[DD];
    {
        int t = threadIdx.x;
        sWr[t] = ((const float4*)Wr3)[t];
        sWl[t] = ((const float4*)Wl3)[t];
        if (t < DD) sb[t] = b3[t];
    }
    __syncthreads();

    int lane = threadIdx.x & 127;
    int half = threadIdx.x >> 7;
    int i = blockIdx.x * 128 + lane;             // 0 .. NB*KK-1 (grid 512)
    int g = perm_int[i];
    float sc = score[g];

    float xv[DD], av[DD];
    {
        const float4* xp = (const float4*)(x + (long long)g * DD);
        const float4* ap = (const float4*)(agg + (long long)g * DD);
#pragma unroll
        for (int q = 0; q < 8; q++) {
            float4 v = xp[q]; xv[4*q]=v.x; xv[4*q+1]=v.y; xv[4*q+2]=v.z; xv[4*q+3]=v.w;
            float4 w = ap[q]; av[4*q]=w.x; av[4*q+1]=w.y; av[4*q+2]=w.z; av[4*q+3]=w.w;
        }
    }

    float* outp = out_x5 + (long long)i * DD;
    int dbase = half * 4;
    for (int dd = 0; dd < 4; dd++) {
        int d0 = dbase + dd;
        float a[4];
#pragma unroll
        for (int j = 0; j < 4; j++) a[j] = sb[4*d0+j];
#pragma unroll
        for (int k = 0; k < DD; k++) {
            float xk = xv[k], ak = av[k];
            float4 wr = sWr[k*8 + d0];
            float4 wl = sWl[k*8 + d0];
            const float* rp = &wr.x; const float* lp = &wl.x;
#pragma unroll
            for (int j = 0; j < 4; j++) {
                a[j] += xk * rp[j];
                a[j] += ak * lp[j];
            }
        }
#pragma unroll
        for (int j = 0; j < 4; j++) outp[4*d0+j] = xv[4*d0+j] + sc * a[j];
    }
}

// ---------------------------------------------------------------------------
// K5: filter_adj — relabel edges, mask dropped. 4 edges/thread, vectorized.
// Runs last; overwrites the agg (out_ei) and edge_ids (out_attr) scratch.
// ---------------------------------------------------------------------------
__global__ __launch_bounds__(256) void edge_kernel(
    const int* __restrict__ src, const int* __restrict__ dst,
    const float* __restrict__ edge_attr,
    const int* __restrict__ new_idx,
    float* __restrict__ out_ei,    // [2*EE]
    float* __restrict__ out_attr)  // [EE]
{
    int e = (blockIdx.x * 256 + threadIdx.x) * 4;
    if (e >= EE) return;
    int4 s4 = *(const int4*)(src + e);
    int4 d4 = *(const int4*)(dst + e);
    float4 at = *(const float4*)(edge_attr + e);

    int ns[4] = { new_idx[s4.x], new_idx[s4.y], new_idx[s4.z], new_idx[s4.w] };
    int nd[4] = { new_idx[d4.x], new_idx[d4.y], new_idx[d4.z], new_idx[d4.w] };
    float av[4] = { at.x, at.y, at.z, at.w };

    float4 os, od, oa;
    float* osp = &os.x; float* odp = &od.x; float* oap = &oa.x;
#pragma unroll
    for (int j = 0; j < 4; j++) {
        bool valid = (ns[j] >= 0) && (nd[j] >= 0);
        osp[j] = (float)(valid ? ns[j] : -1);
        odp[j] = (float)(valid ? nd[j] : -1);
        oap[j] = valid ? av[j] : 0.f;
    }
    *(float4*)(out_ei + e)      = os;
    *(float4*)(out_ei + EE + e) = od;
    *(float4*)(out_attr + e)    = oa;
}

// ---------------------------------------------------------------------------
extern "C" void kernel_launch(void* const* d_in, const int* in_sizes, int n_in,
                              void* d_out, int out_size, void* d_ws, size_t ws_size,
                              hipStream_t stream)
{
    const float* x     = (const float*)d_in[0];         // fp32 [N, D]
    const int*   src   = (const int*)d_in[1];           // edge_index[0]
    const int*   dst   = ((const int*)d_in[1]) + EE;    // edge_index[1]
    const float* eattr = (const float*)d_in[2];         // fp32 [E]
    // d_in[3] = batch (implied: node g belongs to graph g/NPG)
    const float* Wr1 = (const float*)d_in[4];
    const float* Wl1 = (const float*)d_in[5];
    const float* b1  = (const float*)d_in[6];
    const float* Wr2 = (const float*)d_in[7];
    const float* Wl2 = (const float*)d_in[8];
    const float* b2  = (const float*)d_in[9];
    const float* Wr3 = (const float*)d_in[10];
    const float* Wl3 = (const float*)d_in[11];
    const float* b3  = (const float*)d_in[12];

    // ---- workspace layout (total ~6.5 MiB)
    char* ws = (char*)d_ws;
    int*   counts   = (int*)  (ws + 0);                                  // NN*4
    int*   offsets  = (int*)  (ws + (size_t)NN*4);
    float* score    = (float*)(ws + (size_t)NN*8);
    int*   perm_int = (int*)  (ws + (size_t)NN*12);                      // NB*KK*4
    int*   new_idx  = (int*)  (ws + (size_t)NN*12 + (size_t)NB*KK*4);
    int*   hist     = (int*)  (ws + (size_t)NN*16 + (size_t)NB*KK*4);    // 4*NN*4 = 2 MiB
    int*   cursors  = (int*)  (ws + (size_t)NN*32 + (size_t)NB*KK*4);    // 4*NN*4 = 2 MiB

    // ---- output layout: ONE flat fp32 buffer, reference return order
    float* out = (float*)d_out;
    float* out_x5    = out;                       // NB*KK*DD = 2097152
    float* out_ei    = out + (size_t)NB*KK*DD;    // 2*EE     = 4194304
    float* out_attr  = out_ei + (size_t)2*EE;     // EE       = 2097152
    float* out_batch = out_attr + (size_t)EE;     // NB*KK
    float* out_perm  = out_batch + (size_t)NB*KK; // NB*KK
    float* out_score = out_perm + (size_t)NB*KK;  // NB*KK

    // Scratch aliasing into dead output regions (edge_kernel runs last):
    //   agg      = NN*DD fp32 == out_ei region (exact fit)
    //   edge_ids = EE   int32 == out_attr region (exact fit)
    float* agg      = out_ei;
    int*   edge_ids = (int*)out_attr;

    hist_kernel   <<<256, 1024, 0, stream>>>(dst, hist);
    scan2_kernel  <<<NB, 1024, 0, stream>>>(hist, counts, offsets, cursors);
    scatter_kernel<<<256, 1024, 0, stream>>>(src, dst, cursors, edge_ids);

    agg_kernel  <<<(NN*8)/256, 256, 0, stream>>>(x, counts, offsets, edge_ids, agg);

    score_kernel<<<NN/256, 256, 0, stream>>>(x, agg, Wr1, Wl1, b1, Wr2, Wl2, b2, score);

    topk_kernel<<<NB, 1024, 0, stream>>>(score, perm_int, new_idx,
                                         out_perm, out_batch, out_score);

    x5_kernel<<<(NB*KK)/128, 256, 0, stream>>>(x, agg, Wr3, Wl3, b3,
                                               perm_int, score, out_x5);

    edge_kernel<<<(EE/4)/256, 256, 0, stream>>>(src, dst, eattr, new_idx, out_ei, out_attr);
}

// Round 22
// 216.566 us; speedup vs baseline: 1.1379x; 1.1379x over previous
//
#include <hip/hip_runtime.h>
#include <hip/hip_bf16.h>

// Problem constants (from reference)
#define NB   64          // graphs
#define NPG  2048        // nodes per graph
#define NN   (NB*NPG)    // 131072 total nodes
#define EPG  32768       // edges per graph
#define EE   (NB*EPG)    // 2097152 edges
#define DD   32          // feature dim
#define KK   1024        // kept nodes per graph (ratio 0.5)

typedef unsigned long long u64;
typedef unsigned int u32;

// ---------------------------------------------------------------------------
// K1a: per-sub-block histogram. 256 blocks: graph g = b&63, sub s = b>>6,
// 8192 edges each. LDS histogram -> global hist[s][g][n]. Integer atomics
// commute -> counts deterministic.
// ---------------------------------------------------------------------------
__global__ __launch_bounds__(1024) void hist_kernel(
    const int* __restrict__ dst, int* __restrict__ hist)
{
    __shared__ int cnt[NPG];
    int b = blockIdx.x;
    int t = threadIdx.x;
    int g = b & 63, s = b >> 6;
    for (int i = t; i < NPG; i += 1024) cnt[i] = 0;
    __syncthreads();
    const int ebase = g * EPG + s * 8192;
    const int nbase = g * NPG;
#pragma unroll
    for (int q = 0; q < 8; q++) {
        int e = ebase + q * 1024 + t;
        atomicAdd(&cnt[dst[e] - nbase], 1);
    }
    __syncthreads();
    int* hb = hist + (s * 64 + g) * NPG;
    for (int i = t; i < NPG; i += 1024) hb[i] = cnt[i];
}

// ---------------------------------------------------------------------------
// K1b: per-graph scan. 64 blocks. Sums the 4 sub-histograms -> counts,
// exclusive-scans totals -> offsets, and emits per-sub-block start cursors.
// ---------------------------------------------------------------------------
__global__ __launch_bounds__(1024) void scan2_kernel(
    const int* __restrict__ hist,
    int* __restrict__ counts, int* __restrict__ offsets,
    int* __restrict__ cursors)
{
    __shared__ int tot[1024];
    int g = blockIdx.x;
    int t = threadIdx.x;
    int n0 = 2 * t, n1 = 2 * t + 1;
    int h0[4], h1[4];
#pragma unroll
    for (int s = 0; s < 4; s++) {
        h0[s] = hist[(s * 64 + g) * NPG + n0];
        h1[s] = hist[(s * 64 + g) * NPG + n1];
    }
    int c0 = h0[0] + h0[1] + h0[2] + h0[3];
    int c1 = h1[0] + h1[1] + h1[2] + h1[3];
    tot[t] = c0 + c1;
    __syncthreads();
    for (int o = 1; o < 1024; o <<= 1) {
        int v = tot[t];
        int u = (t >= o) ? tot[t - o] : 0;
        __syncthreads();
        tot[t] = v + u;
        __syncthreads();
    }
    int excl = (t == 0) ? 0 : tot[t - 1];
    int nbase = g * NPG;
    counts[nbase + n0] = c0;
    counts[nbase + n1] = c1;
    int off0 = g * EPG + excl;
    int off1 = off0 + c0;
    offsets[nbase + n0] = off0;
    offsets[nbase + n1] = off1;
    int a0 = off0, a1 = off1;
#pragma unroll
    for (int s = 0; s < 4; s++) {
        cursors[(s * 64 + g) * NPG + n0] = a0; a0 += h0[s];
        cursors[(s * 64 + g) * NPG + n1] = a1; a1 += h1[s];
    }
}

// ---------------------------------------------------------------------------
// K1c: scatter. 256 blocks, same (g,s) mapping -> all 4 writer blocks of a
// graph satisfy b%8 == g%8 (same-XCD heuristic) -> no cross-XCD write amp.
// Bucket ORDER from atomics is nondeterministic (multiset is deterministic);
// downstream aggregation is order-INVARIANT (fixed-point) so this is safe.
// ---------------------------------------------------------------------------
__global__ __launch_bounds__(1024) void scatter_kernel(
    const int* __restrict__ src, const int* __restrict__ dst,
    const int* __restrict__ cursors, int* __restrict__ edge_ids)
{
    __shared__ int cur[NPG];
    int b = blockIdx.x;
    int t = threadIdx.x;
    int g = b & 63, s = b >> 6;
    const int* cb = cursors + (s * 64 + g) * NPG;
    for (int i = t; i < NPG; i += 1024) cur[i] = cb[i];
    __syncthreads();
    const int ebase = g * EPG + s * 8192;
    const int nbase = g * NPG;
#pragma unroll
    for (int q = 0; q < 8; q++) {
        int e = ebase + q * 1024 + t;
        int pos = atomicAdd(&cur[dst[e] - nbase], 1);
        edge_ids[pos] = src[e];
    }
}

// ---------------------------------------------------------------------------
// K2a: aggregation — agg[n] = sum_{s in N(n)} x[s]. 8 threads per node.
// FIXED-POINT int32 accumulation (scale 2^22): integer adds commute exactly
// -> agg identical for ANY bucket order -> replay-deterministic (R18 fix).
// Overflow: |sum| <= ~40*8*2^22 ~ 1.3e9 < 2^31. XCD-affinity swizzle.
// ---------------------------------------------------------------------------
__global__ __launch_bounds__(256) void agg_kernel(
    const float* __restrict__ x,
    const int* __restrict__ counts, const int* __restrict__ offsets,
    const int* __restrict__ edge_ids,
    float* __restrict__ agg)
{
    const float SCALE  = 4194304.0f;             // 2^22
    const float ISCALE = 2.38418579101562e-07f;  // 2^-22
    int b = blockIdx.x;                          // 0..4095
    int c = (b & 7) * 512 + (b >> 3);            // bijection on [0,4096)
    int tid = c * 256 + threadIdx.x;             // NN*8 threads
    int node = tid >> 3;
    int ch = (tid & 7) * 4;
    int deg  = counts[node];
    int base = offsets[node];
    int ax = 0, ay = 0, az = 0, aw = 0;
    for (int k = 0; k < deg; k++) {
        int s = edge_ids[base + k];
        float4 v = *(const float4*)(x + (long long)s * DD + ch);
        ax += __float2int_rn(v.x * SCALE);
        ay += __float2int_rn(v.y * SCALE);
        az += __float2int_rn(v.z * SCALE);
        aw += __float2int_rn(v.w * SCALE);
    }
    float4 r;
    r.x = (float)ax * ISCALE;
    r.y = (float)ay * ISCALE;
    r.z = (float)az * ISCALE;
    r.w = (float)aw * ISCALE;
    *(float4*)(agg + (long long)node * DD + ch) = r;
}

// ---------------------------------------------------------------------------
// K2b: per-node score = <x2, y2> / sqrt(32). fp32 W in LDS (ds_read_b128).
// R=2 node-pairing (i, i+NN/2) + 2-way d-split — FINAL form. Measured tree:
// scalar-fma (this, ~36us) beats bf16-W (R13: set-membership corruption),
// global-W (R7), launch-bounds caps (R10: spill), float2 SLP (R16), forced
// v_pk_fma_f32 (R20: VALUBusy 41->15% but 36->44us — the scalar FMA slots
// were the latency filler for ds_read gaps; removing them exposed LDS
// latency worth more than the VALU saved). ESTABLISHED (R13): score must
// stay fp32-accurate; only summation-order changes are safe.
// ---------------------------------------------------------------------------
__global__ __launch_bounds__(256) void score_kernel(
    const float* __restrict__ x, const float* __restrict__ agg,
    const float* __restrict__ Wr1, const float* __restrict__ Wl1, const float* __restrict__ b1,
    const float* __restrict__ Wr2, const float* __restrict__ Wl2, const float* __restrict__ b2,
    float* __restrict__ score)
{
    __shared__ float4 sWr1[DD*DD/4], sWl1[DD*DD/4], sWr2[DD*DD/4], sWl2[DD*DD/4];
    __shared__ float sb1[DD], sb2[DD];
    __shared__ float2 part[128];
    {
        int t = threadIdx.x;             // 256 threads, 256 float4 per matrix
        sWr1[t] = ((const float4*)Wr1)[t];
        sWl1[t] = ((const float4*)Wl1)[t];
        sWr2[t] = ((const float4*)Wr2)[t];
        sWl2[t] = ((const float4*)Wl2)[t];
        if (t < DD) { sb1[t] = b1[t]; sb2[t] = b2[t]; }
    }
    __syncthreads();

    int lane = threadIdx.x & 127;
    int half = threadIdx.x >> 7;                 // 0: d0 0-3, 1: d0 4-7
    int i0 = blockIdx.x * 128 + lane;            // 0 .. NN/2-1
    int i1 = i0 + NN/2;                          // second dense stream

    float xv0[DD], av0[DD], xv1[DD], av1[DD];
    {
        const float4* xp0 = (const float4*)(x + (long long)i0 * DD);
        const float4* ap0 = (const float4*)(agg + (long long)i0 * DD);
        const float4* xp1 = (const float4*)(x + (long long)i1 * DD);
        const float4* ap1 = (const float4*)(agg + (long long)i1 * DD);
#pragma unroll
        for (int q = 0; q < 8; q++) {
            float4 v0 = xp0[q]; xv0[4*q]=v0.x; xv0[4*q+1]=v0.y; xv0[4*q+2]=v0.z; xv0[4*q+3]=v0.w;
            float4 w0 = ap0[q]; av0[4*q]=w0.x; av0[4*q+1]=w0.y; av0[4*q+2]=w0.z; av0[4*q+3]=w0.w;
            float4 v1 = xp1[q]; xv1[4*q]=v1.x; xv1[4*q+1]=v1.y; xv1[4*q+2]=v1.z; xv1[4*q+3]=v1.w;
            float4 w1 = ap1[q]; av1[4*q]=w1.x; av1[4*q+1]=w1.y; av1[4*q+2]=w1.z; av1[4*q+3]=w1.w;
        }
    }

    float sc0 = 0.f, sc1 = 0.f;
    int dbase = half * 4;
    for (int dd = 0; dd < 4; dd++) {             // this thread's 4 d0-blocks
        int d0 = dbase + dd;
        float a0[4], q0[4], a1[4], q1[4];
#pragma unroll
        for (int j = 0; j < 4; j++) {
            a0[j] = sb1[4*d0+j]; q0[j] = sb2[4*d0+j];
            a1[j] = sb1[4*d0+j]; q1[j] = sb2[4*d0+j];
        }
#pragma unroll
        for (int k = 0; k < DD; k++) {
            float4 wr1 = sWr1[k*8 + d0];
            float4 wl1 = sWl1[k*8 + d0];
            float4 wr2 = sWr2[k*8 + d0];
            float4 wl2 = sWl2[k*8 + d0];
            const float* r1 = &wr1.x; const float* l1 = &wl1.x;
            const float* r2 = &wr2.x; const float* l2 = &wl2.x;
            float xk0 = xv0[k], ak0 = av0[k];
            float xk1 = xv1[k], ak1 = av1[k];
#pragma unroll
            for (int j = 0; j < 4; j++) {
                a0[j] += xk0 * r1[j];   // per-d chain order == round 8
                a0[j] += ak0 * l1[j];
                q0[j] += xk0 * r2[j];
                q0[j] += ak0 * l2[j];
                a1[j] += xk1 * r1[j];
                a1[j] += ak1 * l1[j];
                q1[j] += xk1 * r2[j];
                q1[j] += ak1 * l2[j];
            }
        }
#pragma unroll
        for (int j = 0; j < 4; j++) { sc0 += a0[j] * q0[j]; sc1 += a1[j] * q1[j]; }
    }

    if (half) { part[lane].x = sc0; part[lane].y = sc1; }
    __syncthreads();
    if (!half) {
        float2 p = part[lane];
        score[i0] = (sc0 + p.x) * 0.17677669529663687f;   // 1/sqrt(32)
        score[i1] = (sc1 + p.y) * 0.17677669529663687f;
    }
}

// ---------------------------------------------------------------------------
// K3: per-graph top-K via bitonic sort of 2048 packed keys in LDS. Unique
// keys (idx in low bits) -> total order -> deterministic. Also initializes
// new_idx for ALL nodes (kept -> new label, dropped -> -1).
// ---------------------------------------------------------------------------
__global__ __launch_bounds__(1024) void topk_kernel(
    const float* __restrict__ score,
    int* __restrict__ perm_int, int* __restrict__ new_idx,
    float* __restrict__ out_perm,
    float* __restrict__ out_batch,
    float* __restrict__ out_score)
{
    __shared__ u64 keys[NPG];
    int b = blockIdx.x;
    int t = threadIdx.x;
    const float* s = score + (long long)b * NPG;

    for (int j = t; j < NPG; j += 1024) {
        u32 u = __float_as_uint(s[j]);
        u32 h = (u & 0x80000000u) ? u : ~(u | 0x80000000u);
        keys[j] = ((u64)h << 32) | (u32)j;
    }

    for (int k = 2; k <= NPG; k <<= 1) {
        for (int j = k >> 1; j > 0; j >>= 1) {
            __syncthreads();
            int i = ((t & ~(j - 1)) << 1) | (t & (j - 1));
            int l = i | j;
            u64 a = keys[i], c = keys[l];
            bool up = ((i & k) == 0);
            if ((a > c) == up) { keys[i] = c; keys[l] = a; }
        }
    }
    __syncthreads();

    // kept half: ranks 0..KK-1 (thread t owns rank t)
    u64 kk = keys[t];
    int idx = (int)(u32)(kk & 0xFFFFFFFFu);
    int g = b * NPG + idx;
    int o = b * KK + t;
    perm_int[o] = g;
    new_idx[g] = o;
    out_perm[o]  = (float)g;
    out_batch[o] = (float)b;
    out_score[o] = s[idx];

    // dropped half: ranks KK..NPG-1 -> new_idx = -1 (replaces memset)
    u64 kd = keys[t + KK];
    int idxd = (int)(u32)(kd & 0xFFFFFFFFu);
    new_idx[b * NPG + idxd] = -1;
}

// ---------------------------------------------------------------------------
// K4: x5 = x[g] + score[g] * (x[g]@Wr3 + agg[g]@Wl3 + b3), kept nodes only.
// d-split: two threads per node; fp32 W in LDS.
// ---------------------------------------------------------------------------
__global__ __launch_bounds__(256) void x5_kernel(
    const float* __restrict__ x, const float* __restrict__ agg,
    const float* __restrict__ Wr3, const float* __restrict__ Wl3, const float* __restrict__ b3,
    const int* __restrict__ perm_int, const float* __restrict__ score,
    float* __restrict__ out_x5)
{
    __shared__ float4 sWr[DD*DD/4], sWl[DD*DD/4];
    __shared__ float sb[DD];
    {
        int t = threadIdx.x;
        sWr[t] = ((const float4*)Wr3)[t];
        sWl[t] = ((const float4*)Wl3)[t];
        if (t < DD) sb[t] = b3[t];
    }
    __syncthreads();

    int lane = threadIdx.x & 127;
    int half = threadIdx.x >> 7;
    int i = blockIdx.x * 128 + lane;             // 0 .. NB*KK-1 (grid 512)
    int g = perm_int[i];
    float sc = score[g];

    float xv[DD], av[DD];
    {
        const float4* xp = (const float4*)(x + (long long)g * DD);
        const float4* ap = (const float4*)(agg + (long long)g * DD);
#pragma unroll
        for (int q = 0; q < 8; q++) {
            float4 v = xp[q]; xv[4*q]=v.x; xv[4*q+1]=v.y; xv[4*q+2]=v.z; xv[4*q+3]=v.w;
            float4 w = ap[q]; av[4*q]=w.x; av[4*q+1]=w.y; av[4*q+2]=w.z; av[4*q+3]=w.w;
        }
    }

    float* outp = out_x5 + (long long)i * DD;
    int dbase = half * 4;
    for (int dd = 0; dd < 4; dd++) {
        int d0 = dbase + dd;
        float a[4];
#pragma unroll
        for (int j = 0; j < 4; j++) a[j] = sb[4*d0+j];
#pragma unroll
        for (int k = 0; k < DD; k++) {
            float xk = xv[k], ak = av[k];
            float4 wr = sWr[k*8 + d0];
            float4 wl = sWl[k*8 + d0];
            const float* rp = &wr.x; const float* lp = &wl.x;
#pragma unroll
            for (int j = 0; j < 4; j++) {
                a[j] += xk * rp[j];
                a[j] += ak * lp[j];
            }
        }
#pragma unroll
        for (int j = 0; j < 4; j++) outp[4*d0+j] = xv[4*d0+j] + sc * a[j];
    }
}

// ---------------------------------------------------------------------------
// K5: filter_adj — relabel edges, mask dropped. 4 edges/thread, vectorized.
// Runs last; overwrites the agg (out_ei) and edge_ids (out_attr) scratch.
// ---------------------------------------------------------------------------
__global__ __launch_bounds__(256) void edge_kernel(
    const int* __restrict__ src, const int* __restrict__ dst,
    const float* __restrict__ edge_attr,
    const int* __restrict__ new_idx,
    float* __restrict__ out_ei,    // [2*EE]
    float* __restrict__ out_attr)  // [EE]
{
    int e = (blockIdx.x * 256 + threadIdx.x) * 4;
    if (e >= EE) return;
    int4 s4 = *(const int4*)(src + e);
    int4 d4 = *(const int4*)(dst + e);
    float4 at = *(const float4*)(edge_attr + e);

    int ns[4] = { new_idx[s4.x], new_idx[s4.y], new_idx[s4.z], new_idx[s4.w] };
    int nd[4] = { new_idx[d4.x], new_idx[d4.y], new_idx[d4.z], new_idx[d4.w] };
    float av[4] = { at.x, at.y, at.z, at.w };

    float4 os, od, oa;
    float* osp = &os.x; float* odp = &od.x; float* oap = &oa.x;
#pragma unroll
    for (int j = 0; j < 4; j++) {
        bool valid = (ns[j] >= 0) && (nd[j] >= 0);
        osp[j] = (float)(valid ? ns[j] : -1);
        odp[j] = (float)(valid ? nd[j] : -1);
        oap[j] = valid ? av[j] : 0.f;
    }
    *(float4*)(out_ei + e)      = os;
    *(float4*)(out_ei + EE + e) = od;
    *(float4*)(out_attr + e)    = oa;
}

// ---------------------------------------------------------------------------
extern "C" void kernel_launch(void* const* d_in, const int* in_sizes, int n_in,
                              void* d_out, int out_size, void* d_ws, size_t ws_size,
                              hipStream_t stream)
{
    const float* x     = (const float*)d_in[0];         // fp32 [N, D]
    const int*   src   = (const int*)d_in[1];           // edge_index[0]
    const int*   dst   = ((const int*)d_in[1]) + EE;    // edge_index[1]
    const float* eattr = (const float*)d_in[2];         // fp32 [E]
    // d_in[3] = batch (implied: node g belongs to graph g/NPG)
    const float* Wr1 = (const float*)d_in[4];
    const float* Wl1 = (const float*)d_in[5];
    const float* b1  = (const float*)d_in[6];
    const float* Wr2 = (const float*)d_in[7];
    const float* Wl2 = (const float*)d_in[8];
    const float* b2  = (const float*)d_in[9];
    const float* Wr3 = (const float*)d_in[10];
    const float* Wl3 = (const float*)d_in[11];
    const float* b3  = (const float*)d_in[12];

    // ---- workspace layout (total ~6.5 MiB)
    char* ws = (char*)d_ws;
    int*   counts   = (int*)  (ws + 0);                                  // NN*4
    int*   offsets  = (int*)  (ws + (size_t)NN*4);
    float* score    = (float*)(ws + (size_t)NN*8);
    int*   perm_int = (int*)  (ws + (size_t)NN*12);                      // NB*KK*4
    int*   new_idx  = (int*)  (ws + (size_t)NN*12 + (size_t)NB*KK*4);
    int*   hist     = (int*)  (ws + (size_t)NN*16 + (size_t)NB*KK*4);    // 4*NN*4 = 2 MiB
    int*   cursors  = (int*)  (ws + (size_t)NN*32 + (size_t)NB*KK*4);    // 4*NN*4 = 2 MiB

    // ---- output layout: ONE flat fp32 buffer, reference return order
    float* out = (float*)d_out;
    float* out_x5    = out;                       // NB*KK*DD = 2097152
    float* out_ei    = out + (size_t)NB*KK*DD;    // 2*EE     = 4194304
    float* out_attr  = out_ei + (size_t)2*EE;     // EE       = 2097152
    float* out_batch = out_attr + (size_t)EE;     // NB*KK
    float* out_perm  = out_batch + (size_t)NB*KK; // NB*KK
    float* out_score = out_perm + (size_t)NB*KK;  // NB*KK

    // Scratch aliasing into dead output regions (edge_kernel runs last):
    //   agg      = NN*DD fp32 == out_ei region (exact fit)
    //   edge_ids = EE   int32 == out_attr region (exact fit)
    float* agg      = out_ei;
    int*   edge_ids = (int*)out_attr;

    hist_kernel   <<<256, 1024, 0, stream>>>(dst, hist);
    scan2_kernel  <<<NB, 1024, 0, stream>>>(hist, counts, offsets, cursors);
    scatter_kernel<<<256, 1024, 0, stream>>>(src, dst, cursors, edge_ids);

    agg_kernel  <<<(NN*8)/256, 256, 0, stream>>>(x, counts, offsets, edge_ids, agg);

    score_kernel<<<NN/256, 256, 0, stream>>>(x, agg, Wr1, Wl1, b1, Wr2, Wl2, b2, score);

    topk_kernel<<<NB, 1024, 0, stream>>>(score, perm_int, new_idx,
                                         out_perm, out_batch, out_score);

    x5_kernel<<<(NB*KK)/128, 256, 0, stream>>>(x, agg, Wr3, Wl3, b3,
                                               perm_int, score, out_x5);

    edge_kernel<<<(EE/4)/256, 256, 0, stream>>>(src, dst, eattr, new_idx, out_ei, out_attr);
}